// Round 6
// baseline (240.124 us; speedup 1.0000x reference)
//
#include <hip/hip_runtime.h>
#include <stdint.h>

typedef unsigned short u16;
typedef __attribute__((ext_vector_type(8))) short short8;
typedef __attribute__((ext_vector_type(4))) float f32x4;

#define MFMA(a, b, c) __builtin_amdgcn_mfma_f32_16x16x32_bf16((a), (b), (c), 0, 0, 0)

#if __has_builtin(__builtin_amdgcn_exp2f)
#define EXP2(x) __builtin_amdgcn_exp2f(x)
#else
#define EXP2(x) exp2f(x)
#endif

__device__ __forceinline__ u16 f2bf(float f) {
  union { float f; unsigned int u; } v; v.f = f;
  unsigned int r = v.u + 0x7fffu + ((v.u >> 16) & 1u);
  return (u16)(r >> 16);
}

// pack two fp32 -> two bf16 in one u32 (round-half-up)
__device__ __forceinline__ unsigned int pk2bf(float a, float b) {
  union { float f; unsigned int u; } va, vb; va.f = a; vb.f = b;
  return __builtin_amdgcn_perm(vb.u + 0x8000u, va.u + 0x8000u, 0x07060302u);
}

__device__ __forceinline__ void gl_lds16(const void* g, void* l) {
  __builtin_amdgcn_global_load_lds(
      (const __attribute__((address_space(1))) void*)g,
      (__attribute__((address_space(3))) void*)l, 16, 0, 0);
}

// ---------------- fp32 -> bf16 convert ----------------
__global__ __launch_bounds__(256) void cvt_bf16(const float* __restrict__ s,
                                                u16* __restrict__ d, int n) {
  int i = (blockIdx.x * 256 + threadIdx.x) * 8;
  if (i >= n) return;
  float4 a = *(const float4*)(s + i);
  float4 b = *(const float4*)(s + i + 4);
  ushort4 o0, o1;
  o0.x = f2bf(a.x); o0.y = f2bf(a.y); o0.z = f2bf(a.z); o0.w = f2bf(a.w);
  o1.x = f2bf(b.x); o1.y = f2bf(b.y); o1.z = f2bf(b.z); o1.w = f2bf(b.w);
  *(ushort4*)(d + i) = o0;
  *(ushort4*)(d + i + 4) = o1;
}

// ---------------- qkv GEMM: [8192,768] x [2304,768]^T ----------------
// q scaled by 0.125*log2(e); v written TRANSPOSED (vt[bh][d][n]) through an
// LDS-staged [o][m] tile so the global writes are 16B-coalesced along n.
__global__ __launch_bounds__(256) void gemm_qkv(
    const u16* __restrict__ A, const u16* __restrict__ W,
    u16* __restrict__ qb, u16* __restrict__ kb, u16* __restrict__ vtb) {
  __shared__ u16 smem[128 * 136];  // K-loop: As=smem[0:4096], Bs=smem[4096:8192]
  u16* As = smem;                  // v-epilogue: reused as [o][m] stride-136 tile
  u16* Bs = smem + 4096;
  constexpr int K = 768;
  const int m0 = blockIdx.x * 128, n0 = blockIdx.y * 128;
  const int t = threadIdx.x;
  const int lane = t & 63, w = t >> 6;
  const int l15 = lane & 15, q4 = lane >> 4;
  const int wm = w >> 1, wn = w & 1;
  f32x4 acc[4][4] = {};
  for (int k0 = 0; k0 < K; k0 += 32) {
    __syncthreads();
#pragma unroll
    for (int p = 0; p < 2; p++) {
      int C = p * 256 + t;
      int r = C >> 2;
      int gcol = ((C & 3) ^ (r & 3)) << 3;  // 16B-chunk XOR swizzle
      gl_lds16(A + (size_t)(m0 + r) * K + (k0 + gcol), &As[(p * 256 + (t & ~63)) * 8]);
      gl_lds16(W + (size_t)(n0 + r) * K + (k0 + gcol), &Bs[(p * 256 + (t & ~63)) * 8]);
    }
    __syncthreads();
    short8 af[4], bfr[4];
#pragma unroll
    for (int i = 0; i < 4; i++) {
      int ra = wm * 64 + i * 16 + l15;
      af[i] = *(const short8*)&As[(ra * 4 + (q4 ^ (ra & 3))) * 8];
      int rb = wn * 64 + i * 16 + l15;
      bfr[i] = *(const short8*)&Bs[(rb * 4 + (q4 ^ (rb & 3))) * 8];
    }
#pragma unroll
    for (int mi = 0; mi < 4; mi++)
#pragma unroll
      for (int ni = 0; ni < 4; ni++)
        acc[mi][ni] = MFMA(af[mi], bfr[ni], acc[mi][ni]);
  }
  const int sec = n0 / 768;  // block-uniform: 0=q 1=k 2=v
  const int ob = n0 % 768;
  if (sec == 2) {
    // ---- v: stage [o][m] in LDS (stride 136), then coalesced vt writes ----
    __syncthreads();  // all waves done reading As/Bs
#pragma unroll
    for (int mi = 0; mi < 4; mi++) {
      const int mb = wm * 64 + mi * 16 + q4 * 4;
#pragma unroll
      for (int ni = 0; ni < 4; ni++) {
        const int o = wn * 64 + ni * 16 + l15;
        uint2 pk;
        pk.x = pk2bf(acc[mi][ni][0], acc[mi][ni][1]);
        pk.y = pk2bf(acc[mi][ni][2], acc[mi][ni][3]);
        *(uint2*)&smem[o * 136 + mb] = pk;
      }
    }
    __syncthreads();
    const int bloc = m0 >> 11, nn0 = m0 & 2047;
#pragma unroll
    for (int it = 0; it < 8; it++) {
      const int o = it * 16 + (t >> 4);   // 0..127
      const int c = (t & 15) * 8;         // m-chunk base
      const int gog = ob + o, h = gog >> 6, d = gog & 63;
      uint4 vv = *(const uint4*)&smem[o * 136 + c];
      *(uint4*)&vtb[((size_t)(bloc * 12 + h) * 64 + d) * 2048 + nn0 + c] = vv;
    }
  } else {
    u16* __restrict__ dst = (sec == 0) ? qb : kb;
    const float scl = (sec == 0) ? 0.18033688011f : 1.0f;  // 0.125 * log2(e)
#pragma unroll
    for (int mi = 0; mi < 4; mi++) {
      const int mbase = m0 + wm * 64 + mi * 16 + q4 * 4;
#pragma unroll
      for (int ni = 0; ni < 4; ni++) {
        const int o = ob + wn * 64 + ni * 16 + l15;
        const int h = o >> 6, d = o & 63;
#pragma unroll
        for (int i = 0; i < 4; i++) {
          const int mm = mbase + i;
          const int b = mm >> 11, n = mm & 2047;
          dst[((size_t)(b * 12 + h) * 2048 + n) * 64 + d] = f2bf(acc[mi][ni][i] * scl);
        }
      }
    }
  }
}

// ---------------- flash attention ----------------
// grid (16 q-tiles, 48 bh); 4 waves x 32 q-rows; KV tile = 64.
// Double-buffered K/V staging with ONE barrier per tile: at the barrier the
// wave's own DMA (issued a full compute-phase earlier) is drained, and all
// waves are done reading the other buffer. DMA latency hides under compute.
// P at stride 72 (b128 reads tile the banks; b64 writes 2-way = free).
// Row-sums via MFMA ones-column (C-layout match with oacc -> no shuffles).
__global__ __launch_bounds__(256) void attn(
    const u16* __restrict__ q, const u16* __restrict__ k,
    const u16* __restrict__ vt, u16* __restrict__ ao) {
  __shared__ u16 kbuf[2][64 * 64];   // [buf][kv][d] swizzled 16B chunks
  __shared__ u16 vtbuf[2][64 * 64];  // [buf][d][kv] swizzled 16B chunks
  __shared__ u16 pbuf[4][32 * 72];   // per-wave P [qrow][kv], stride 72
  const int qt = blockIdx.x, bh = blockIdx.y;
  const int t = threadIdx.x, w = t >> 6, lane = t & 63;
  const int l15 = lane & 15, q4 = lane >> 4;

  // Q fragments (register-resident)
  const u16* qp = q + ((size_t)bh * 2048 + qt * 128 + w * 32) * 64;
  short8 qf[2][2];
#pragma unroll
  for (int mi = 0; mi < 2; mi++)
#pragma unroll
    for (int ks = 0; ks < 2; ks++)
      qf[mi][ks] = *(const short8*)&qp[(mi * 16 + l15) * 64 + ks * 32 + q4 * 8];

  // DMA source pointers (advance by += per tile)
  const u16* kbase = k + (size_t)bh * 2048 * 64;
  const u16* vbase = vt + (size_t)bh * 64 * 2048;
  const int r0 = t >> 3;                     // 0..31
  const int gc = ((t & 7) ^ (r0 & 7)) << 3;  // swizzled 16B chunk in row
  const u16* kp0 = kbase + r0 * 64 + gc;
  const u16* kp1 = kbase + (r0 + 32) * 64 + gc;
  const u16* vp0 = vbase + (size_t)r0 * 2048 + gc;
  const u16* vp1 = vbase + (size_t)(r0 + 32) * 2048 + gc;
  const int wdst = (w * 64 & ~63) * 8;  // wave-uniform dest base (elems)

  // preload tile 0 into buf 0
  gl_lds16(kp0, &kbuf[0][wdst]);
  gl_lds16(kp1, &kbuf[0][2048 + wdst]);
  gl_lds16(vp0, &vtbuf[0][wdst]);
  gl_lds16(vp1, &vtbuf[0][2048 + wdst]);
  kp0 += 4096; kp1 += 4096; vp0 += 64; vp1 += 64;

  u16* pw = &pbuf[w][0];
  f32x4 oacc[2][4] = {};
  f32x4 osum[2] = {};  // row sums, same C-layout rows as oacc
  const f32x4 z4 = {0.f, 0.f, 0.f, 0.f};
  union { unsigned int u[4]; short8 s; } ones;
  ones.u[0] = ones.u[1] = ones.u[2] = ones.u[3] = 0x3F803F80u;  // bf16 1.0 x8
  int cur = 0;
#pragma unroll 2
  for (int kt = 0; kt < 32; kt++) {
    __syncthreads();  // drains own vmcnt -> buf[cur] ready; buf[cur^1] reads done
    if (kt < 31) {
      const int nxt = cur ^ 1;
      gl_lds16(kp0, &kbuf[nxt][wdst]);
      gl_lds16(kp1, &kbuf[nxt][2048 + wdst]);
      gl_lds16(vp0, &vtbuf[nxt][wdst]);
      gl_lds16(vp1, &vtbuf[nxt][2048 + wdst]);
      kp0 += 4096; kp1 += 4096; vp0 += 64; vp1 += 64;
    }
    const u16* kl = &kbuf[cur][0];
    const u16* vl = &vtbuf[cur][0];
    // S^T = K Q^T : C-layout lane owns qrow=l15, kv=nf*16+q4*4+i
    f32x4 sacc[2][4];
#pragma unroll
    for (int nf = 0; nf < 4; nf++) {
      int rb = nf * 16 + l15;
      short8 k0 = *(const short8*)&kl[(rb * 8 + (q4 ^ (rb & 7))) * 8];
      short8 k1 = *(const short8*)&kl[(rb * 8 + ((4 + q4) ^ (rb & 7))) * 8];
      sacc[0][nf] = MFMA(k0, qf[0][0], z4);
      sacc[0][nf] = MFMA(k1, qf[0][1], sacc[0][nf]);
      sacc[1][nf] = MFMA(k0, qf[1][0], z4);
      sacc[1][nf] = MFMA(k1, qf[1][1], sacc[1][nf]);
    }
    // p = exp2(s); pack; b64 writes (2-way aliasing only -> free)
#pragma unroll
    for (int mi = 0; mi < 2; mi++) {
#pragma unroll
      for (int nf = 0; nf < 4; nf++) {
        f32x4 p;
        p[0] = EXP2(sacc[mi][nf][0]);
        p[1] = EXP2(sacc[mi][nf][1]);
        p[2] = EXP2(sacc[mi][nf][2]);
        p[3] = EXP2(sacc[mi][nf][3]);
        uint2 pk;
        pk.x = pk2bf(p[0], p[1]);
        pk.y = pk2bf(p[2], p[3]);
        *(uint2*)&pw[(mi * 16 + l15) * 72 + nf * 16 + q4 * 4] = pk;
      }
    }
    // O += P V ; row-sums += P * ones  (pbuf wave-private: no barrier)
#pragma unroll
    for (int ks2 = 0; ks2 < 2; ks2++) {
      short8 pf0 = *(const short8*)&pw[l15 * 72 + ks2 * 32 + q4 * 8];
      short8 pf1 = *(const short8*)&pw[(16 + l15) * 72 + ks2 * 32 + q4 * 8];
#pragma unroll
      for (int df = 0; df < 4; df++) {
        int rv = df * 16 + l15;
        short8 vf = *(const short8*)&vl[(rv * 8 + ((ks2 * 4 + q4) ^ (rv & 7))) * 8];
        oacc[0][df] = MFMA(pf0, vf, oacc[0][df]);
        oacc[1][df] = MFMA(pf1, vf, oacc[1][df]);
      }
      osum[0] = MFMA(pf0, ones.s, osum[0]);
      osum[1] = MFMA(pf1, ones.s, osum[1]);
    }
    cur ^= 1;
  }
  // normalize: osum[mi][i] is the row-sum for qrow = mi*16 + q4*4 + i
  const int b = bh / 12, h = bh % 12;
#pragma unroll
  for (int mi = 0; mi < 2; mi++) {
    float linv[4];
#pragma unroll
    for (int i = 0; i < 4; i++) linv[i] = __builtin_amdgcn_rcpf(osum[mi][i]);
#pragma unroll
    for (int df = 0; df < 4; df++)
#pragma unroll
      for (int i = 0; i < 4; i++) {
        int n = qt * 128 + w * 32 + mi * 16 + q4 * 4 + i;
        float val = oacc[mi][df][i] * linv[i];
        ao[((size_t)b * 2048 + n) * 768 + h * 64 + df * 16 + l15] = f2bf(val);
      }
  }
}

// ---------------- proj GEMM: [8192,768] x [768,768]^T + bias -> fp32 ----------------
// 64x128 tile -> grid 128x6 = 768 blocks (3/CU)
__global__ __launch_bounds__(256) void gemm_proj(
    const u16* __restrict__ A, const u16* __restrict__ W,
    const float* __restrict__ bias, float* __restrict__ out) {
  __shared__ u16 As[64 * 32], Bs[128 * 32];
  constexpr int K = 768;
  const int m0 = blockIdx.x * 64, n0 = blockIdx.y * 128;
  const int t = threadIdx.x;
  const int lane = t & 63, w = t >> 6;
  const int l15 = lane & 15, q4 = lane >> 4;
  const int wm = w >> 1, wn = w & 1;
  f32x4 acc[2][4] = {};
  for (int k0 = 0; k0 < K; k0 += 32) {
    __syncthreads();
    {  // As: 64 rows x 4 chunks (1 load/thread)
      int r = t >> 2;
      int gcol = ((t & 3) ^ (r & 3)) << 3;
      gl_lds16(A + (size_t)(m0 + r) * K + (k0 + gcol), &As[(t & ~63) * 8]);
    }
#pragma unroll
    for (int p = 0; p < 2; p++) {  // Bs: 128 rows x 4 chunks (2 loads/thread)
      int C = p * 256 + t;
      int r = C >> 2;
      int gcol = ((C & 3) ^ (r & 3)) << 3;
      gl_lds16(W + (size_t)(n0 + r) * K + (k0 + gcol), &Bs[(p * 256 + (t & ~63)) * 8]);
    }
    __syncthreads();
    short8 af[2], bfr[4];
#pragma unroll
    for (int i = 0; i < 2; i++) {
      int ra = wm * 32 + i * 16 + l15;
      af[i] = *(const short8*)&As[(ra * 4 + (q4 ^ (ra & 3))) * 8];
    }
#pragma unroll
    for (int i = 0; i < 4; i++) {
      int rb = wn * 64 + i * 16 + l15;
      bfr[i] = *(const short8*)&Bs[(rb * 4 + (q4 ^ (rb & 3))) * 8];
    }
#pragma unroll
    for (int mi = 0; mi < 2; mi++)
#pragma unroll
      for (int ni = 0; ni < 4; ni++)
        acc[mi][ni] = MFMA(af[mi], bfr[ni], acc[mi][ni]);
  }
  float bsv[4];
#pragma unroll
  for (int ni = 0; ni < 4; ni++) bsv[ni] = bias[n0 + wn * 64 + ni * 16 + l15];
#pragma unroll
  for (int mi = 0; mi < 2; mi++) {
    const int mbase = m0 + wm * 32 + mi * 16 + q4 * 4;
#pragma unroll
    for (int ni = 0; ni < 4; ni++) {
      const int o = n0 + wn * 64 + ni * 16 + l15;
#pragma unroll
      for (int i = 0; i < 4; i++)
        out[(size_t)(mbase + i) * 768 + o] = acc[mi][ni][i] + bsv[ni];
    }
  }
}

extern "C" void kernel_launch(void* const* d_in, const int* in_sizes, int n_in,
                              void* d_out, int out_size, void* d_ws, size_t ws_size,
                              hipStream_t stream) {
  const float* x = (const float*)d_in[0];      // [4,2048,768]
  const float* wqkv = (const float*)d_in[1];   // [2304,768]
  const float* wproj = (const float*)d_in[2];  // [768,768]
  const float* bproj = (const float*)d_in[3];  // [768]
  float* out = (float*)d_out;                  // [4,2048,768] fp32

  char* ws = (char*)d_ws;
  u16* xb    = (u16*)(ws + 0);         // 6291456 elems
  u16* wqkvb = (u16*)(ws + 12582912);  // 1769472
  u16* wprojb= (u16*)(ws + 16121856);  // 589824
  u16* qb    = (u16*)(ws + 17301504);  // 6291456 (pre-scaled)
  u16* kb    = (u16*)(ws + 29884416);  // 6291456
  u16* vtb   = (u16*)(ws + 42467328);  // 6291456 (v transposed [bh][d][n])
  u16* aob   = (u16*)(ws + 55050240);  // 6291456
  // total ws use: 67633152 bytes

  cvt_bf16<<<3072, 256, 0, stream>>>(x, xb, 6291456);
  cvt_bf16<<<864, 256, 0, stream>>>(wqkv, wqkvb, 1769472);
  cvt_bf16<<<288, 256, 0, stream>>>(wproj, wprojb, 589824);
  gemm_qkv<<<dim3(64, 18), 256, 0, stream>>>(xb, wqkvb, qb, kb, vtb);
  attn<<<dim3(16, 48), 256, 0, stream>>>(qb, kb, vtb, aob);
  gemm_proj<<<dim3(128, 6), 256, 0, stream>>>(aob, wprojb, bproj, out);
}